// Round 2
// baseline (3296.056 us; speedup 1.0000x reference)
//
#include <hip/hip_runtime.h>
#include <hip/hip_bf16.h>

#define N_USERS   50000
#define N_ITEMS   100000
#define N_NODES   150000
#define DIM       64
#define N_INTENTS 128
#define N_EDGES   3000000

static __device__ __forceinline__ float wsum64(float v){
#pragma unroll
  for (int m = 32; m >= 1; m >>= 1) v += __shfl_xor(v, m, 64);
  return v;
}
static __device__ __forceinline__ float wmax64(float v){
#pragma unroll
  for (int m = 32; m >= 1; m >>= 1) v = fmaxf(v, __shfl_xor(v, m, 64));
  return v;
}

// emb = concat(user_emb, item_emb); acc(=d_out) = emb
__global__ void k_init(const float* __restrict__ ue, const float* __restrict__ ie,
                       float* __restrict__ emb, float* __restrict__ acc){
  int i = blockIdx.x * 256 + threadIdx.x;
  if (i >= N_NODES * DIM) return;
  float v = (i < N_USERS * DIM) ? ue[i] : ie[i - N_USERS * DIM];
  emb[i] = v; acc[i] = v;
}

__global__ void k_deg(const int* __restrict__ h, int* __restrict__ deg){
  int e = blockIdx.x * 256 + threadIdx.x;
  if (e < N_EDGES) atomicAdd(&deg[h[e]], 1);
}

// per-block inclusive scan of deg (256/block), block totals to aux
__global__ void k_scan1(const int* __restrict__ deg, int* __restrict__ tmp,
                        int* __restrict__ aux){
  __shared__ int s[256];
  int t = threadIdx.x, i = blockIdx.x * 256 + t;
  int v = (i < N_NODES) ? deg[i] : 0;
  s[t] = v; __syncthreads();
  for (int off = 1; off < 256; off <<= 1){
    int x = (t >= off) ? s[t - off] : 0;
    __syncthreads();
    s[t] += x;
    __syncthreads();
  }
  if (i < N_NODES) tmp[i] = s[t];
  if (t == 255) aux[blockIdx.x] = s[255];
}

// single-block exclusive scan of aux (n <= 1024)
__global__ __launch_bounds__(1024) void k_scan2(int* __restrict__ aux, int n){
  __shared__ int s[1024];
  int t = threadIdx.x;
  int v = (t < n) ? aux[t] : 0;
  s[t] = v; __syncthreads();
  for (int off = 1; off < 1024; off <<= 1){
    int x = (t >= off) ? s[t - off] : 0;
    __syncthreads();
    s[t] += x;
    __syncthreads();
  }
  if (t < n) aux[t] = s[t] - v;   // exclusive
}

__global__ void k_rowptr(const int* __restrict__ tmp, const int* __restrict__ deg,
                         const int* __restrict__ aux, int* __restrict__ rp,
                         int* __restrict__ cur){
  int i = blockIdx.x * 256 + threadIdx.x;
  if (i < N_NODES){
    int v = aux[i >> 8] + tmp[i] - deg[i];
    rp[i] = v; cur[i] = v;
  }
  if (i == 0) rp[N_NODES] = N_EDGES;
}

__global__ void k_scatter(const int* __restrict__ h, const int* __restrict__ t,
                          int* __restrict__ cur, int* __restrict__ h_csr,
                          int* __restrict__ t_csr){
  int e = blockIdx.x * 256 + threadIdx.x;
  if (e >= N_EDGES) return;
  int hh = h[e];
  int pos = atomicAdd(&cur[hh], 1);
  h_csr[pos] = hh; t_csr[pos] = t[e];
}

__global__ void k_dis(const int* __restrict__ deg, float* __restrict__ dis){
  int n = blockIdx.x * 256 + threadIdx.x;
  if (n < N_NODES){ int d = deg[n]; dis[n] = (d > 0) ? (1.f / sqrtf((float)d)) : 0.f; }
}

// gnn[n] = dis[n] * sum_e dis[t_e] * emb[t_e]   (one wave per node, lane = dim)
__global__ void k_spmm_gnn(const int* __restrict__ rp, const int* __restrict__ t_csr,
                           const float* __restrict__ dis, const float* __restrict__ emb,
                           float* __restrict__ gnn){
  int w = (blockIdx.x * 256 + threadIdx.x) >> 6;
  int lane = threadIdx.x & 63;
  if (w >= N_NODES) return;
  int s = rp[w], e = rp[w + 1];
  float acc = 0.f;
  for (int i = s; i < e; i++){
    int t = t_csr[i];
    acc = fmaf(dis[t], emb[t * DIM + lane], acc);
  }
  gnn[w * DIM + lane] = dis[w] * acc;
}

// out[n] = softmax(emb[n] @ W) @ W^T  for n in [base_node, base_node+count)
// W is (DIM=64, N_INTENTS=128); LDS copy with stride 129 (129 % 32 == 1 ->
// both d-major (pass A) and j-major (pass B) accesses are 2-way = conflict-free).
__global__ __launch_bounds__(256) void k_intent(const float* __restrict__ W,
                                                const float* __restrict__ emb,
                                                float* __restrict__ out,
                                                int base_node, int count){
  __shared__ float Wl[DIM * 129];
  __shared__ float el[4][DIM];
  __shared__ float pl[4][N_INTENTS];
  int tid = threadIdx.x;
  for (int i = tid; i < DIM * N_INTENTS; i += 256){
    int d = i >> 7, j = i & 127;
    Wl[d * 129 + j] = W[i];
  }
  __syncthreads();
  int wv = tid >> 6, lane = tid & 63;
  for (int base = blockIdx.x * 4; base < count; base += gridDim.x * 4){
    int n = base + wv;
    bool act = (n < count);
    if (act) el[wv][lane] = emb[(base_node + n) * DIM + lane];
    __syncthreads();
    float L0 = 0.f, L1 = 0.f;
    if (act){
#pragma unroll
      for (int d = 0; d < DIM; d++){
        float e = el[wv][d];
        L0 = fmaf(e, Wl[d * 129 + lane], L0);
        L1 = fmaf(e, Wl[d * 129 + lane + 64], L1);
      }
    }
    float m = wmax64(fmaxf(L0, L1));
    float p0 = __expf(L0 - m), p1 = __expf(L1 - m);
    float inv = 1.f / wsum64(p0 + p1);
    if (act){ pl[wv][lane] = p0; pl[wv][lane + 64] = p1; }
    __syncthreads();
    if (act){
      float o = 0.f;
#pragma unroll
      for (int j = 0; j < N_INTENTS; j++)
        o = fmaf(pl[wv][j], Wl[lane * 129 + j], o);
      out[(base_node + n) * DIM + lane] = o * inv;
    }
    __syncthreads();
  }
}

// per-node inverse L2 norms for gnn and int_e (one wave per node)
__global__ void k_invnorm(const float* __restrict__ gnn, const float* __restrict__ inte,
                          float* __restrict__ ing, float* __restrict__ ini){
  int w = (blockIdx.x * 256 + threadIdx.x) >> 6;
  int lane = threadIdx.x & 63;
  if (w >= N_NODES) return;
  float g = gnn[w * DIM + lane];
  float i = inte[w * DIM + lane];
  float sg = wsum64(g * g);
  float si = wsum64(i * i);
  if (lane == 0){
    ing[w] = 1.f / fmaxf(sqrtf(sg), 1e-8f);
    ini[w] = 1.f / fmaxf(sqrtf(si), 1e-8f);
  }
}

// per-edge alpha for both adaptive passes (one wave per edge, lane = dim)
__global__ void k_edgedot(const int* __restrict__ h_csr, const int* __restrict__ t_csr,
                          const float* __restrict__ gnn, const float* __restrict__ inte,
                          const float* __restrict__ ing, const float* __restrict__ ini,
                          float2* __restrict__ a12){
  int w = (blockIdx.x * 256 + threadIdx.x) >> 6;
  int lane = threadIdx.x & 63;
  if (w >= N_EDGES) return;
  int hh = h_csr[w], tt = t_csr[w];
  float dg = wsum64(gnn[hh * DIM + lane] * gnn[tt * DIM + lane]);
  float di = wsum64(inte[hh * DIM + lane] * inte[tt * DIM + lane]);
  if (lane == 0){
    float a1 = 0.5f * (dg * ing[hh] * ing[tt] + 1.f);
    float a2 = 0.5f * (di * ini[hh] * ini[tt] + 1.f);
    a12[w] = make_float2(a1, a2);
  }
}

// per-node row sums of alpha -> d_inv (one thread per node; rows contiguous in CSR)
__global__ void k_rowsum(const int* __restrict__ rp, const float2* __restrict__ a12,
                         float* __restrict__ d1, float* __restrict__ d2){
  int n = blockIdx.x * 256 + threadIdx.x;
  if (n >= N_NODES) return;
  float s1 = 0.f, s2 = 0.f;
  int e0 = rp[n], e1 = rp[n + 1];
  for (int e = e0; e < e1; e++){ float2 a = a12[e]; s1 += a.x; s2 += a.y; }
  d1[n] = (s1 > 0.f) ? 1.f / s1 : 0.f;
  d2[n] = (s2 > 0.f) ? 1.f / s2 : 0.f;
}

// new_emb = gnn + int_e + emb + d1*sum(a1*emb[t]) + d2*sum(a2*emb[t]); acc += new_emb
// writes new_emb in place over the gnn buffer (each thread reads only its own idx)
__global__ void k_fuse(const int* __restrict__ rp, const int* __restrict__ t_csr,
                       const float2* __restrict__ a12,
                       const float* __restrict__ d1, const float* __restrict__ d2,
                       const float* __restrict__ inte, const float* __restrict__ emb,
                       float* __restrict__ gnn_io, float* __restrict__ acc){
  int w = (blockIdx.x * 256 + threadIdx.x) >> 6;
  int lane = threadIdx.x & 63;
  if (w >= N_NODES) return;
  int s = rp[w], e = rp[w + 1];
  float s1 = 0.f, s2 = 0.f;
  for (int i = s; i < e; i++){
    int t = t_csr[i];
    float2 a = a12[i];
    float v = emb[t * DIM + lane];
    s1 = fmaf(a.x, v, s1);
    s2 = fmaf(a.y, v, s2);
  }
  int idx = w * DIM + lane;
  float nv = gnn_io[idx] + inte[idx] + emb[idx] + d1[w] * s1 + d2[w] * s2;
  gnn_io[idx] = nv;
  acc[idx] += nv;
}

extern "C" void kernel_launch(void* const* d_in, const int* in_sizes, int n_in,
                              void* d_out, int out_size, void* d_ws, size_t ws_size,
                              hipStream_t stream){
  const float* ue = (const float*)d_in[0];
  const float* ie = (const float*)d_in[1];
  const float* wu = (const float*)d_in[2];
  const float* wi = (const float*)d_in[3];
  const int* all_h = (const int*)d_in[4];
  const int* all_t = (const int*)d_in[5];
  float* acc = (float*)d_out;   // acc lives directly in d_out (fp32 output)

  char* p = (char*)d_ws;
  auto take = [&](size_t bytes)->char*{
    char* r = p; p += (bytes + 255) & ~size_t(255); return r;
  };
  float*  embA = (float*)take(sizeof(float) * N_NODES * DIM);
  float*  embB = (float*)take(sizeof(float) * N_NODES * DIM);
  float*  inte = (float*)take(sizeof(float) * N_NODES * DIM);
  float2* a12  = (float2*)take(sizeof(float2) * N_EDGES);
  int*    h_csr = (int*)take(sizeof(int) * N_EDGES);
  int*    t_csr = (int*)take(sizeof(int) * N_EDGES);
  float*  dis  = (float*)take(sizeof(float) * N_NODES);
  float*  ing  = (float*)take(sizeof(float) * N_NODES);
  float*  ini  = (float*)take(sizeof(float) * N_NODES);
  float*  d1   = (float*)take(sizeof(float) * N_NODES);
  float*  d2   = (float*)take(sizeof(float) * N_NODES);
  int*    deg  = (int*)take(sizeof(int) * N_NODES);
  int*    tmp  = (int*)take(sizeof(int) * N_NODES);
  int*    aux  = (int*)take(sizeof(int) * 1024);
  int*    rp   = (int*)take(sizeof(int) * (N_NODES + 1));
  int*    cur  = (int*)take(sizeof(int) * N_NODES);
  if ((size_t)(p - (char*)d_ws) > ws_size) return;  // fail loudly, not corruptly

  const int ELEM_B  = (N_NODES * DIM + 255) / 256;  // elementwise over 9.6M
  const int NODEW_B = (N_NODES * 64 + 255) / 256;   // wave per node
  const int EDGE_B  = (N_EDGES + 255) / 256;
  const int EDGEW_B = (N_EDGES * 64 + 255) / 256;   // wave per edge
  const int NODE_B  = (N_NODES + 255) / 256;

  hipMemsetAsync(deg, 0, sizeof(int) * N_NODES, stream);
  k_init<<<ELEM_B, 256, 0, stream>>>(ue, ie, embA, acc);
  k_deg<<<EDGE_B, 256, 0, stream>>>(all_h, deg);
  k_scan1<<<NODE_B, 256, 0, stream>>>(deg, tmp, aux);
  k_scan2<<<1, 1024, 0, stream>>>(aux, NODE_B);
  k_rowptr<<<NODE_B, 256, 0, stream>>>(tmp, deg, aux, rp, cur);
  k_scatter<<<EDGE_B, 256, 0, stream>>>(all_h, all_t, cur, h_csr, t_csr);
  k_dis<<<NODE_B, 256, 0, stream>>>(deg, dis);

  float* eA = embA;  // current emb
  float* eB = embB;  // gnn / next emb
  for (int layer = 0; layer < 2; layer++){
    k_spmm_gnn<<<NODEW_B, 256, 0, stream>>>(rp, t_csr, dis, eA, eB);
    k_intent<<<1024, 256, 0, stream>>>(wu, eA, inte, 0, N_USERS);
    k_intent<<<1024, 256, 0, stream>>>(wi, eA, inte, N_USERS, N_ITEMS);
    k_invnorm<<<NODEW_B, 256, 0, stream>>>(eB, inte, ing, ini);
    k_edgedot<<<EDGEW_B, 256, 0, stream>>>(h_csr, t_csr, eB, inte, ing, ini, a12);
    k_rowsum<<<NODE_B, 256, 0, stream>>>(rp, a12, d1, d2);
    k_fuse<<<NODEW_B, 256, 0, stream>>>(rp, t_csr, a12, d1, d2, inte, eA, eB, acc);
    float* t = eA; eA = eB; eB = t;
  }
}

// Round 3
// 2362.256 us; speedup vs baseline: 1.3953x; 1.3953x over previous
//
#include <hip/hip_runtime.h>
#include <hip/hip_bf16.h>

#define N_USERS   50000
#define N_ITEMS   100000
#define N_NODES   150000
#define DIM       64
#define N_INTENTS 128
#define N_EDGES   3000000

static __device__ __forceinline__ float wsum64(float v){
#pragma unroll
  for (int m = 32; m >= 1; m >>= 1) v += __shfl_xor(v, m, 64);
  return v;
}
static __device__ __forceinline__ float wmax64(float v){
#pragma unroll
  for (int m = 32; m >= 1; m >>= 1) v = fmaxf(v, __shfl_xor(v, m, 64));
  return v;
}

// bf16 pack/unpack (RNE via hip intrinsic for pack; unpack = shift)
static __device__ __forceinline__ unsigned short f2bf(float x){
  __hip_bfloat16 h = __float2bfloat16(x);
  return __builtin_bit_cast(unsigned short, h);
}
static __device__ __forceinline__ float bf_lo(unsigned int v){
  return __builtin_bit_cast(float, v << 16);
}
static __device__ __forceinline__ float bf_hi(unsigned int v){
  return __builtin_bit_cast(float, v & 0xFFFF0000u);
}

// emb = concat(user_emb, item_emb); acc(=d_out) = emb
__global__ void k_init(const float* __restrict__ ue, const float* __restrict__ ie,
                       float* __restrict__ emb, float* __restrict__ acc){
  int i = blockIdx.x * 256 + threadIdx.x;
  if (i >= N_NODES * DIM) return;
  float v = (i < N_USERS * DIM) ? ue[i] : ie[i - N_USERS * DIM];
  emb[i] = v; acc[i] = v;
}

__global__ void k_deg(const int* __restrict__ h, int* __restrict__ deg){
  int e = blockIdx.x * 256 + threadIdx.x;
  if (e < N_EDGES) atomicAdd(&deg[h[e]], 1);
}

// per-block inclusive scan of deg (256/block), block totals to aux
__global__ void k_scan1(const int* __restrict__ deg, int* __restrict__ tmp,
                        int* __restrict__ aux){
  __shared__ int s[256];
  int t = threadIdx.x, i = blockIdx.x * 256 + t;
  int v = (i < N_NODES) ? deg[i] : 0;
  s[t] = v; __syncthreads();
  for (int off = 1; off < 256; off <<= 1){
    int x = (t >= off) ? s[t - off] : 0;
    __syncthreads();
    s[t] += x;
    __syncthreads();
  }
  if (i < N_NODES) tmp[i] = s[t];
  if (t == 255) aux[blockIdx.x] = s[255];
}

// single-block exclusive scan of aux (n <= 1024)
__global__ __launch_bounds__(1024) void k_scan2(int* __restrict__ aux, int n){
  __shared__ int s[1024];
  int t = threadIdx.x;
  int v = (t < n) ? aux[t] : 0;
  s[t] = v; __syncthreads();
  for (int off = 1; off < 1024; off <<= 1){
    int x = (t >= off) ? s[t - off] : 0;
    __syncthreads();
    s[t] += x;
    __syncthreads();
  }
  if (t < n) aux[t] = s[t] - v;   // exclusive
}

__global__ void k_rowptr(const int* __restrict__ tmp, const int* __restrict__ deg,
                         const int* __restrict__ aux, int* __restrict__ rp,
                         int* __restrict__ cur, float* __restrict__ dis){
  int i = blockIdx.x * 256 + threadIdx.x;
  if (i < N_NODES){
    int v = aux[i >> 8] + tmp[i] - deg[i];
    rp[i] = v; cur[i] = v;
    int d = deg[i];
    dis[i] = (d > 0) ? (1.f / sqrtf((float)d)) : 0.f;
  }
  if (i == 0) rp[N_NODES] = N_EDGES;
}

__global__ void k_scatter(const int* __restrict__ h, const int* __restrict__ t,
                          int* __restrict__ cur, int* __restrict__ t_csr){
  int e = blockIdx.x * 256 + threadIdx.x;
  if (e >= N_EDGES) return;
  int pos = atomicAdd(&cur[h[e]], 1);
  t_csr[pos] = t[e];
}

// gnn[n] = dis[n] * sum_e dis[t_e] * emb[t_e]  (wave per node, lane = dim)
// + inline L2-normalize of the result -> packed bf16 low half of hgig
__global__ void k_spmm_gnn(const int* __restrict__ rp, const int* __restrict__ t_csr,
                           const float* __restrict__ dis, const float* __restrict__ emb,
                           float* __restrict__ gnn, unsigned short* __restrict__ hgig_s){
  int w = (blockIdx.x * 256 + threadIdx.x) >> 6;
  int lane = threadIdx.x & 63;
  if (w >= N_NODES) return;
  int s = rp[w], e = rp[w + 1];
  float acc = 0.f;
  for (int i = s; i < e; i++){
    int t = t_csr[i];
    acc = fmaf(dis[t], emb[t * DIM + lane], acc);
  }
  float gv = dis[w] * acc;
  int idx = w * DIM + lane;
  gnn[idx] = gv;
  float nrm = wsum64(gv * gv);
  float invn = 1.f / fmaxf(sqrtf(nrm), 1e-8f);
  hgig_s[idx * 2] = f2bf(gv * invn);       // low half of the packed dword
}

// out[n] = softmax(emb[n] @ W) @ W^T ; + inline L2-normalize -> high half of hgig
// W is (64,128); LDS stride 129 -> conflict-free both passes.
__global__ __launch_bounds__(256) void k_intent(const float* __restrict__ W,
                                                const float* __restrict__ emb,
                                                float* __restrict__ out,
                                                unsigned short* __restrict__ hgig_s,
                                                int base_node, int count){
  __shared__ float Wl[DIM * 129];
  __shared__ float el[4][DIM];
  __shared__ float pl[4][N_INTENTS];
  int tid = threadIdx.x;
  for (int i = tid; i < DIM * N_INTENTS; i += 256){
    int d = i >> 7, j = i & 127;
    Wl[d * 129 + j] = W[i];
  }
  __syncthreads();
  int wv = tid >> 6, lane = tid & 63;
  for (int base = blockIdx.x * 4; base < count; base += gridDim.x * 4){
    int n = base + wv;
    bool act = (n < count);
    if (act) el[wv][lane] = emb[(base_node + n) * DIM + lane];
    __syncthreads();
    float L0 = 0.f, L1 = 0.f;
    if (act){
#pragma unroll
      for (int d = 0; d < DIM; d++){
        float e = el[wv][d];
        L0 = fmaf(e, Wl[d * 129 + lane], L0);
        L1 = fmaf(e, Wl[d * 129 + lane + 64], L1);
      }
    }
    float m = wmax64(fmaxf(L0, L1));
    float p0 = __expf(L0 - m), p1 = __expf(L1 - m);
    float inv = 1.f / wsum64(p0 + p1);
    if (act){ pl[wv][lane] = p0; pl[wv][lane + 64] = p1; }
    __syncthreads();
    if (act){
      float o = 0.f;
#pragma unroll
      for (int j = 0; j < N_INTENTS; j++)
        o = fmaf(pl[wv][j], Wl[lane * 129 + j], o);
      float v = o * inv;
      int idx = (base_node + n) * DIM + lane;
      out[idx] = v;
      float nrm = wsum64(v * v);
      float invn = 1.f / fmaxf(sqrtf(nrm), 1e-8f);
      hgig_s[idx * 2 + 1] = f2bf(v * invn); // high half of the packed dword
    }
    __syncthreads();
  }
}

// Fused adaptive passes + residual + acc (wave per row, lane = dim):
// per edge: 1 packed-norm gather + 1 emb gather + dual 6-level butterfly ->
// a1,a2; running rowsums r1,r2 (wave-uniform) and weighted sums s1,s2.
// new = gnn + inte + emb + s1/r1 + s2/r2; written in place over gnn buffer.
__global__ void k_adafuse(const int* __restrict__ rp, const int* __restrict__ t_csr,
                          const unsigned int* __restrict__ hgig,
                          const float* __restrict__ inte, const float* __restrict__ emb,
                          float* __restrict__ gnn_io, float* __restrict__ acc){
  int w = (blockIdx.x * 256 + threadIdx.x) >> 6;
  int lane = threadIdx.x & 63;
  if (w >= N_NODES) return;
  unsigned int hp = hgig[w * DIM + lane];
  float hg = bf_lo(hp), hi = bf_hi(hp);
  int s = rp[w], e = rp[w + 1];
  float s1 = 0.f, s2 = 0.f, r1 = 0.f, r2 = 0.f;
  for (int i = s; i < e; i++){
    int t = t_csr[i];
    unsigned int tp = hgig[t * DIM + lane];
    float ev = emb[t * DIM + lane];
    float p = hg * bf_lo(tp);
    float q = hi * bf_hi(tp);
#pragma unroll
    for (int m = 32; m >= 1; m >>= 1){
      p += __shfl_xor(p, m, 64);
      q += __shfl_xor(q, m, 64);
    }
    float a1 = fmaf(p, 0.5f, 0.5f);
    float a2 = fmaf(q, 0.5f, 0.5f);
    r1 += a1; r2 += a2;
    s1 = fmaf(a1, ev, s1);
    s2 = fmaf(a2, ev, s2);
  }
  float d1 = (r1 > 0.f) ? 1.f / r1 : 0.f;
  float d2 = (r2 > 0.f) ? 1.f / r2 : 0.f;
  int idx = w * DIM + lane;
  float nv = gnn_io[idx] + inte[idx] + emb[idx] + d1 * s1 + d2 * s2;
  gnn_io[idx] = nv;
  acc[idx] += nv;
}

extern "C" void kernel_launch(void* const* d_in, const int* in_sizes, int n_in,
                              void* d_out, int out_size, void* d_ws, size_t ws_size,
                              hipStream_t stream){
  const float* ue = (const float*)d_in[0];
  const float* ie = (const float*)d_in[1];
  const float* wu = (const float*)d_in[2];
  const float* wi = (const float*)d_in[3];
  const int* all_h = (const int*)d_in[4];
  const int* all_t = (const int*)d_in[5];
  float* acc = (float*)d_out;   // acc lives directly in d_out (fp32 output)

  char* p = (char*)d_ws;
  auto take = [&](size_t bytes)->char*{
    char* r = p; p += (bytes + 255) & ~size_t(255); return r;
  };
  float*  embA  = (float*)take(sizeof(float) * N_NODES * DIM);
  float*  embB  = (float*)take(sizeof(float) * N_NODES * DIM);
  float*  inte  = (float*)take(sizeof(float) * N_NODES * DIM);
  unsigned int* hgig = (unsigned int*)take(sizeof(unsigned int) * N_NODES * DIM);
  int*    t_csr = (int*)take(sizeof(int) * N_EDGES);
  float*  dis   = (float*)take(sizeof(float) * N_NODES);
  int*    deg   = (int*)take(sizeof(int) * N_NODES);
  int*    tmp   = (int*)take(sizeof(int) * N_NODES);
  int*    aux   = (int*)take(sizeof(int) * 1024);
  int*    rp    = (int*)take(sizeof(int) * (N_NODES + 1));
  int*    cur   = (int*)take(sizeof(int) * N_NODES);
  if ((size_t)(p - (char*)d_ws) > ws_size) return;  // fail loudly, not corruptly

  const int ELEM_B  = (N_NODES * DIM + 255) / 256;
  const int NODEW_B = (N_NODES * 64 + 255) / 256;   // wave per node
  const int EDGE_B  = (N_EDGES + 255) / 256;
  const int NODE_B  = (N_NODES + 255) / 256;

  hipMemsetAsync(deg, 0, sizeof(int) * N_NODES, stream);
  k_init<<<ELEM_B, 256, 0, stream>>>(ue, ie, embA, acc);
  k_deg<<<EDGE_B, 256, 0, stream>>>(all_h, deg);
  k_scan1<<<NODE_B, 256, 0, stream>>>(deg, tmp, aux);
  k_scan2<<<1, 1024, 0, stream>>>(aux, NODE_B);
  k_rowptr<<<NODE_B, 256, 0, stream>>>(tmp, deg, aux, rp, cur, dis);
  k_scatter<<<EDGE_B, 256, 0, stream>>>(all_h, all_t, cur, t_csr);

  float* eA = embA;  // current emb
  float* eB = embB;  // gnn / next emb
  for (int layer = 0; layer < 2; layer++){
    k_spmm_gnn<<<NODEW_B, 256, 0, stream>>>(rp, t_csr, dis, eA, eB,
                                            (unsigned short*)hgig);
    k_intent<<<(N_USERS + 3) / 4, 256, 0, stream>>>(wu, eA, inte,
                                                    (unsigned short*)hgig, 0, N_USERS);
    k_intent<<<(N_ITEMS + 3) / 4, 256, 0, stream>>>(wi, eA, inte,
                                                    (unsigned short*)hgig, N_USERS, N_ITEMS);
    k_adafuse<<<NODEW_B, 256, 0, stream>>>(rp, t_csr, hgig, inte, eA, eB, acc);
    float* t = eA; eA = eB; eB = t;
  }
}

// Round 4
// 1704.019 us; speedup vs baseline: 1.9343x; 1.3863x over previous
//
#include <hip/hip_runtime.h>
#include <hip/hip_bf16.h>

#define N_USERS   50000
#define N_ITEMS   100000
#define N_NODES   150000
#define DIM       64
#define N_INTENTS 128
#define N_EDGES   3000000

static __device__ __forceinline__ float wsum64(float v){
#pragma unroll
  for (int m = 32; m >= 1; m >>= 1) v += __shfl_xor(v, m, 64);
  return v;
}
static __device__ __forceinline__ float wmax64(float v){
#pragma unroll
  for (int m = 32; m >= 1; m >>= 1) v = fmaxf(v, __shfl_xor(v, m, 64));
  return v;
}

// ---- DPP 16-lane row reduction (full-rate VALU, ~4cyc/step vs ~25 for swizzle)
template<int CTRL>
static __device__ __forceinline__ float dpp_ror_add(float x){
  int t = __builtin_amdgcn_update_dpp(0, __builtin_bit_cast(int, x),
                                      CTRL, 0xF, 0xF, true);
  return x + __builtin_bit_cast(float, t);
}
// sum over the 16-lane DPP row; result identical in all 16 lanes
static __device__ __forceinline__ float row16_allsum(float x){
  x = dpp_ror_add<0x128>(x);  // row_ror:8
  x = dpp_ror_add<0x124>(x);  // row_ror:4
  x = dpp_ror_add<0x122>(x);  // row_ror:2
  x = dpp_ror_add<0x121>(x);  // row_ror:1
  return x;
}

// bf16 pack/unpack
static __device__ __forceinline__ unsigned short f2bf(float x){
  __hip_bfloat16 h = __float2bfloat16(x);
  return __builtin_bit_cast(unsigned short, h);
}
static __device__ __forceinline__ float bf_lo(unsigned int v){
  return __builtin_bit_cast(float, v << 16);
}
static __device__ __forceinline__ float bf_hi(unsigned int v){
  return __builtin_bit_cast(float, v & 0xFFFF0000u);
}

// emb = concat(user_emb, item_emb); acc(=d_out) = emb
__global__ void k_init(const float* __restrict__ ue, const float* __restrict__ ie,
                       float* __restrict__ emb, float* __restrict__ acc){
  int i = blockIdx.x * 256 + threadIdx.x;
  if (i >= N_NODES * DIM) return;
  float v = (i < N_USERS * DIM) ? ue[i] : ie[i - N_USERS * DIM];
  emb[i] = v; acc[i] = v;
}

__global__ void k_deg(const int* __restrict__ h, int* __restrict__ deg){
  int e = blockIdx.x * 256 + threadIdx.x;
  if (e < N_EDGES) atomicAdd(&deg[h[e]], 1);
}

__global__ void k_scan1(const int* __restrict__ deg, int* __restrict__ tmp,
                        int* __restrict__ aux){
  __shared__ int s[256];
  int t = threadIdx.x, i = blockIdx.x * 256 + t;
  int v = (i < N_NODES) ? deg[i] : 0;
  s[t] = v; __syncthreads();
  for (int off = 1; off < 256; off <<= 1){
    int x = (t >= off) ? s[t - off] : 0;
    __syncthreads();
    s[t] += x;
    __syncthreads();
  }
  if (i < N_NODES) tmp[i] = s[t];
  if (t == 255) aux[blockIdx.x] = s[255];
}

__global__ __launch_bounds__(1024) void k_scan2(int* __restrict__ aux, int n){
  __shared__ int s[1024];
  int t = threadIdx.x;
  int v = (t < n) ? aux[t] : 0;
  s[t] = v; __syncthreads();
  for (int off = 1; off < 1024; off <<= 1){
    int x = (t >= off) ? s[t - off] : 0;
    __syncthreads();
    s[t] += x;
    __syncthreads();
  }
  if (t < n) aux[t] = s[t] - v;   // exclusive
}

__global__ void k_rowptr(const int* __restrict__ tmp, const int* __restrict__ deg,
                         const int* __restrict__ aux, int* __restrict__ rp,
                         int* __restrict__ cur, float* __restrict__ dis){
  int i = blockIdx.x * 256 + threadIdx.x;
  if (i < N_NODES){
    int v = aux[i >> 8] + tmp[i] - deg[i];
    rp[i] = v; cur[i] = v;
    int d = deg[i];
    dis[i] = (d > 0) ? (1.f / sqrtf((float)d)) : 0.f;
  }
  if (i == 0) rp[N_NODES] = N_EDGES;
}

__global__ void k_scatter(const int* __restrict__ h, const int* __restrict__ t,
                          int* __restrict__ cur, int* __restrict__ t_csr){
  int e = blockIdx.x * 256 + threadIdx.x;
  if (e >= N_EDGES) return;
  int pos = atomicAdd(&cur[h[e]], 1);
  t_csr[pos] = t[e];
}

// gnn[n] = dis[n] * sum_e dis[t_e] * emb[t_e]
// Slot layout: wave = 4 edge-slots x 16 lanes, lane covers 4 dims (float4).
// + inline L2-normalize -> packed bf16 low halves of hgig.
__global__ void k_spmm_gnn(const int* __restrict__ rp, const int* __restrict__ t_csr,
                           const float* __restrict__ dis, const float* __restrict__ emb,
                           float* __restrict__ gnn, unsigned short* __restrict__ hgig_s){
  int w = (blockIdx.x * 256 + threadIdx.x) >> 6;
  int lane = threadIdx.x & 63;
  if (w >= N_NODES) return;
  int slot = lane >> 4, sub = lane & 15;
  int s = rp[w], e = rp[w + 1];
  float4 a = make_float4(0.f, 0.f, 0.f, 0.f);
  const float4* emb4 = (const float4*)emb;
  for (int i = s + slot; i < e; i += 4){
    int t = t_csr[i];
    float wt = dis[t];
    float4 ev = emb4[t * 16 + sub];
    a.x = fmaf(wt, ev.x, a.x);
    a.y = fmaf(wt, ev.y, a.y);
    a.z = fmaf(wt, ev.z, a.z);
    a.w = fmaf(wt, ev.w, a.w);
  }
#pragma unroll
  for (int m = 16; m <= 32; m <<= 1){
    a.x += __shfl_xor(a.x, m, 64);
    a.y += __shfl_xor(a.y, m, 64);
    a.z += __shfl_xor(a.z, m, 64);
    a.w += __shfl_xor(a.w, m, 64);
  }
  float dw = dis[w];
  float4 gv = make_float4(dw * a.x, dw * a.y, dw * a.z, dw * a.w);
  // row norm: every lane has its sub's 4 dims (identical across slots)
  float sq = gv.x * gv.x + gv.y * gv.y + gv.z * gv.z + gv.w * gv.w;
  float nrm = row16_allsum(sq);
  float invn = 1.f / fmaxf(sqrtf(nrm), 1e-8f);
  if (slot == 0){
    ((float4*)gnn)[w * 16 + sub] = gv;
    int base = (w * DIM + 4 * sub) * 2;
    hgig_s[base]     = f2bf(gv.x * invn);
    hgig_s[base + 2] = f2bf(gv.y * invn);
    hgig_s[base + 4] = f2bf(gv.z * invn);
    hgig_s[base + 6] = f2bf(gv.w * invn);
  }
}

// out[n] = softmax(emb[n] @ W) @ W^T ; + inline L2-normalize -> high half of hgig
__global__ __launch_bounds__(256) void k_intent(const float* __restrict__ W,
                                                const float* __restrict__ emb,
                                                float* __restrict__ out,
                                                unsigned short* __restrict__ hgig_s,
                                                int base_node, int count){
  __shared__ float Wl[DIM * 129];
  __shared__ float el[4][DIM];
  __shared__ float pl[4][N_INTENTS];
  int tid = threadIdx.x;
  for (int i = tid; i < DIM * N_INTENTS; i += 256){
    int d = i >> 7, j = i & 127;
    Wl[d * 129 + j] = W[i];
  }
  __syncthreads();
  int wv = tid >> 6, lane = tid & 63;
  for (int base = blockIdx.x * 4; base < count; base += gridDim.x * 4){
    int n = base + wv;
    bool act = (n < count);
    if (act) el[wv][lane] = emb[(base_node + n) * DIM + lane];
    __syncthreads();
    float L0 = 0.f, L1 = 0.f;
    if (act){
#pragma unroll
      for (int d = 0; d < DIM; d++){
        float e = el[wv][d];
        L0 = fmaf(e, Wl[d * 129 + lane], L0);
        L1 = fmaf(e, Wl[d * 129 + lane + 64], L1);
      }
    }
    float m = wmax64(fmaxf(L0, L1));
    float p0 = __expf(L0 - m), p1 = __expf(L1 - m);
    float inv = 1.f / wsum64(p0 + p1);
    if (act){ pl[wv][lane] = p0; pl[wv][lane + 64] = p1; }
    __syncthreads();
    if (act){
      float o = 0.f;
#pragma unroll
      for (int j = 0; j < N_INTENTS; j++)
        o = fmaf(pl[wv][j], Wl[lane * 129 + j], o);
      float v = o * inv;
      int idx = (base_node + n) * DIM + lane;
      out[idx] = v;
      float nrm = wsum64(v * v);
      float invn = 1.f / fmaxf(sqrtf(nrm), 1e-8f);
      hgig_s[idx * 2 + 1] = f2bf(v * invn);
    }
    __syncthreads();
  }
}

// Fused adaptive passes + residual + acc.
// Slot layout: 4 edge-slots x 16 lanes x float4 dims. Per edge: one uint4
// packed-norm gather + one float4 emb gather; dual dot via 4-step DPP row
// reduce (all 4 edges reduce simultaneously). Cross-slot combine once/row.
__global__ void k_adafuse(const int* __restrict__ rp, const int* __restrict__ t_csr,
                          const uint4* __restrict__ hgig4,
                          const float* __restrict__ inte, const float* __restrict__ emb,
                          float* __restrict__ gnn_io, float* __restrict__ acc){
  int w = (blockIdx.x * 256 + threadIdx.x) >> 6;
  int lane = threadIdx.x & 63;
  if (w >= N_NODES) return;
  int slot = lane >> 4, sub = lane & 15;
  uint4 hp = hgig4[w * 16 + sub];
  float hg0 = bf_lo(hp.x), hg1 = bf_lo(hp.y), hg2 = bf_lo(hp.z), hg3 = bf_lo(hp.w);
  float hi0 = bf_hi(hp.x), hi1 = bf_hi(hp.y), hi2 = bf_hi(hp.z), hi3 = bf_hi(hp.w);
  int s = rp[w], e = rp[w + 1];
  const float4* emb4 = (const float4*)emb;
  float4 s1 = make_float4(0.f, 0.f, 0.f, 0.f);
  float4 s2 = make_float4(0.f, 0.f, 0.f, 0.f);
  float r1 = 0.f, r2 = 0.f;
  for (int i = s + slot; i < e; i += 4){
    int t = t_csr[i];
    uint4 tp = hgig4[t * 16 + sub];
    float4 ev = emb4[t * 16 + sub];
    float p = hg0 * bf_lo(tp.x) + hg1 * bf_lo(tp.y)
            + hg2 * bf_lo(tp.z) + hg3 * bf_lo(tp.w);
    float q = hi0 * bf_hi(tp.x) + hi1 * bf_hi(tp.y)
            + hi2 * bf_hi(tp.z) + hi3 * bf_hi(tp.w);
    p = row16_allsum(p);
    q = row16_allsum(q);
    float a1 = fmaf(p, 0.5f, 0.5f);
    float a2 = fmaf(q, 0.5f, 0.5f);
    r1 += a1; r2 += a2;
    s1.x = fmaf(a1, ev.x, s1.x); s1.y = fmaf(a1, ev.y, s1.y);
    s1.z = fmaf(a1, ev.z, s1.z); s1.w = fmaf(a1, ev.w, s1.w);
    s2.x = fmaf(a2, ev.x, s2.x); s2.y = fmaf(a2, ev.y, s2.y);
    s2.z = fmaf(a2, ev.z, s2.z); s2.w = fmaf(a2, ev.w, s2.w);
  }
#pragma unroll
  for (int m = 16; m <= 32; m <<= 1){
    s1.x += __shfl_xor(s1.x, m, 64); s1.y += __shfl_xor(s1.y, m, 64);
    s1.z += __shfl_xor(s1.z, m, 64); s1.w += __shfl_xor(s1.w, m, 64);
    s2.x += __shfl_xor(s2.x, m, 64); s2.y += __shfl_xor(s2.y, m, 64);
    s2.z += __shfl_xor(s2.z, m, 64); s2.w += __shfl_xor(s2.w, m, 64);
    r1   += __shfl_xor(r1,   m, 64); r2   += __shfl_xor(r2,   m, 64);
  }
  float d1 = (r1 > 0.f) ? 1.f / r1 : 0.f;
  float d2 = (r2 > 0.f) ? 1.f / r2 : 0.f;
  if (slot == 0){
    int idx4 = w * 16 + sub;
    float4 g = ((float4*)gnn_io)[idx4];
    float4 it = ((const float4*)inte)[idx4];
    float4 em = emb4[idx4];
    float4 nv;
    nv.x = g.x + it.x + em.x + d1 * s1.x + d2 * s2.x;
    nv.y = g.y + it.y + em.y + d1 * s1.y + d2 * s2.y;
    nv.z = g.z + it.z + em.z + d1 * s1.z + d2 * s2.z;
    nv.w = g.w + it.w + em.w + d1 * s1.w + d2 * s2.w;
    ((float4*)gnn_io)[idx4] = nv;
    float4 ac = ((float4*)acc)[idx4];
    ac.x += nv.x; ac.y += nv.y; ac.z += nv.z; ac.w += nv.w;
    ((float4*)acc)[idx4] = ac;
  }
}

extern "C" void kernel_launch(void* const* d_in, const int* in_sizes, int n_in,
                              void* d_out, int out_size, void* d_ws, size_t ws_size,
                              hipStream_t stream){
  const float* ue = (const float*)d_in[0];
  const float* ie = (const float*)d_in[1];
  const float* wu = (const float*)d_in[2];
  const float* wi = (const float*)d_in[3];
  const int* all_h = (const int*)d_in[4];
  const int* all_t = (const int*)d_in[5];
  float* acc = (float*)d_out;

  char* p = (char*)d_ws;
  auto take = [&](size_t bytes)->char*{
    char* r = p; p += (bytes + 255) & ~size_t(255); return r;
  };
  float*  embA  = (float*)take(sizeof(float) * N_NODES * DIM);
  float*  embB  = (float*)take(sizeof(float) * N_NODES * DIM);
  float*  inte  = (float*)take(sizeof(float) * N_NODES * DIM);
  unsigned int* hgig = (unsigned int*)take(sizeof(unsigned int) * N_NODES * DIM);
  int*    t_csr = (int*)take(sizeof(int) * N_EDGES);
  float*  dis   = (float*)take(sizeof(float) * N_NODES);
  int*    deg   = (int*)take(sizeof(int) * N_NODES);
  int*    tmp   = (int*)take(sizeof(int) * N_NODES);
  int*    aux   = (int*)take(sizeof(int) * 1024);
  int*    rp    = (int*)take(sizeof(int) * (N_NODES + 1));
  int*    cur   = (int*)take(sizeof(int) * N_NODES);
  if ((size_t)(p - (char*)d_ws) > ws_size) return;

  const int ELEM_B  = (N_NODES * DIM + 255) / 256;
  const int NODEW_B = (N_NODES * 64 + 255) / 256;
  const int EDGE_B  = (N_EDGES + 255) / 256;
  const int NODE_B  = (N_NODES + 255) / 256;

  hipMemsetAsync(deg, 0, sizeof(int) * N_NODES, stream);
  k_init<<<ELEM_B, 256, 0, stream>>>(ue, ie, embA, acc);
  k_deg<<<EDGE_B, 256, 0, stream>>>(all_h, deg);
  k_scan1<<<NODE_B, 256, 0, stream>>>(deg, tmp, aux);
  k_scan2<<<1, 1024, 0, stream>>>(aux, NODE_B);
  k_rowptr<<<NODE_B, 256, 0, stream>>>(tmp, deg, aux, rp, cur, dis);
  k_scatter<<<EDGE_B, 256, 0, stream>>>(all_h, all_t, cur, t_csr);

  float* eA = embA;
  float* eB = embB;
  for (int layer = 0; layer < 2; layer++){
    k_spmm_gnn<<<NODEW_B, 256, 0, stream>>>(rp, t_csr, dis, eA, eB,
                                            (unsigned short*)hgig);
    k_intent<<<(N_USERS + 3) / 4, 256, 0, stream>>>(wu, eA, inte,
                                                    (unsigned short*)hgig, 0, N_USERS);
    k_intent<<<(N_ITEMS + 3) / 4, 256, 0, stream>>>(wi, eA, inte,
                                                    (unsigned short*)hgig, N_USERS, N_ITEMS);
    k_adafuse<<<NODEW_B, 256, 0, stream>>>(rp, t_csr, (const uint4*)hgig,
                                           inte, eA, eB, acc);
    float* t = eA; eA = eB; eB = t;
  }
}